// Round 1
// baseline (1375.525 us; speedup 1.0000x reference)
//
#include <hip/hip_runtime.h>
#include <hip/hip_bf16.h>
#include <cstdint>
#include <type_traits>

#define DIM    4096
#define NHEADS 32
#define NKVH   8
#define HD     128
#define BATCH  2
#define SEQ    2048
#define MROWS  (BATCH*SEQ)      // 4096
#define NQKV   6144             // DIM + 2*NKVH*HD
#define KOFF   4096
#define VOFF   5120

typedef __attribute__((ext_vector_type(8))) __bf16 bf16x8;
typedef __attribute__((ext_vector_type(4))) float  f32x4;

// scale folded into Q: log2(e)/sqrt(HD) so softmax uses exp2 (native v_exp_f32)
#define QSCALE 0.1275174338f

__device__ __forceinline__ void gl_lds16(const __bf16* g, __bf16* l) {
    __builtin_amdgcn_global_load_lds(
        (const __attribute__((address_space(1))) void*)g,
        (__attribute__((address_space(3))) void*)l, 16, 0, 0);
}

// ---------------- fp32 -> bf16 cast (8 elem/thread) ----------------
__global__ void cast_f32_bf16(const float* __restrict__ s, __bf16* __restrict__ d, int n8) {
    int i = blockIdx.x * 256 + threadIdx.x;
    if (i >= n8) return;
    float4 a = ((const float4*)s)[2*i];
    float4 b = ((const float4*)s)[2*i+1];
    bf16x8 v;
    v[0]=(__bf16)a.x; v[1]=(__bf16)a.y; v[2]=(__bf16)a.z; v[3]=(__bf16)a.w;
    v[4]=(__bf16)b.x; v[5]=(__bf16)b.y; v[6]=(__bf16)b.z; v[7]=(__bf16)b.w;
    ((bf16x8*)d)[i] = v;
}

// ---------------- GEMM: C[m,n] = sum_k A[m,k]*B[n,k]  (both row-major, K contig) ----
// m97 structure: 128x128 tile, BK=64, 4 waves, 4x4 16x16x32 MFMA per wave.
template<typename OutT>
__global__ __launch_bounds__(256)
void gemm_bt(const __bf16* __restrict__ A, const __bf16* __restrict__ Bm,
             OutT* __restrict__ C, int M, int N, int K,
             float scale, int scale_cols)
{
    __shared__ __bf16 As[128*64];
    __shared__ __bf16 Bs[128*64];
    const int tid  = threadIdx.x;
    const int lane = tid & 63;
    const int w    = tid >> 6;
    const int quad = lane >> 4;
    const int l16  = lane & 15;
    const int m0   = blockIdx.y * 128;
    const int n0   = blockIdx.x * 128;
    const int wm   = (w & 1) * 64;
    const int wn   = (w >> 1) * 64;

    const __bf16* Ab = A  + (size_t)m0 * K;
    const __bf16* Bb = Bm + (size_t)n0 * K;

    f32x4 acc[4][4] = {};

    for (int k0 = 0; k0 < K; k0 += 64) {
        __syncthreads();
        #pragma unroll
        for (int r = 0; r < 4; ++r) {
            int chunk = r*256 + tid;
            int row = chunk >> 3, c8 = chunk & 7;
            gl_lds16(Ab + (size_t)row*K + k0 + c8*8, As + chunk*8);
            gl_lds16(Bb + (size_t)row*K + k0 + c8*8, Bs + chunk*8);
        }
        __syncthreads();
        #pragma unroll
        for (int kk = 0; kk < 64; kk += 32) {
            bf16x8 af[4], bfr[4];
            #pragma unroll
            for (int i = 0; i < 4; ++i)
                af[i] = *(const bf16x8*)(As + (wm + i*16 + l16)*64 + kk + quad*8);
            #pragma unroll
            for (int j = 0; j < 4; ++j)
                bfr[j] = *(const bf16x8*)(Bs + (wn + j*16 + l16)*64 + kk + quad*8);
            #pragma unroll
            for (int i = 0; i < 4; ++i)
                #pragma unroll
                for (int j = 0; j < 4; ++j)
                    acc[i][j] = __builtin_amdgcn_mfma_f32_16x16x32_bf16(af[i], bfr[j], acc[i][j], 0,0,0);
        }
    }

    // C/D layout: col = lane&15, row = quad*4 + reg  [verified m89/m91]
    #pragma unroll
    for (int i = 0; i < 4; ++i) {
        #pragma unroll
        for (int j = 0; j < 4; ++j) {
            int col = n0 + wn + j*16 + l16;
            float sc = (col < scale_cols) ? scale : 1.0f;
            #pragma unroll
            for (int r = 0; r < 4; ++r) {
                int row = m0 + wm + i*16 + quad*4 + r;
                float v = acc[i][j][r] * sc;
                if constexpr (std::is_same<OutT, float>::value)
                    C[(size_t)row * N + col] = v;
                else
                    C[(size_t)row * N + col] = (__bf16)v;
            }
        }
    }
}

// ---------------- V transpose: vt[(b*8+g)*128 + d][s] = qkv[b*T+s][VOFF + g*128 + d] ----
__global__ void transpose_v(const __bf16* __restrict__ qkv, __bf16* __restrict__ vt) {
    int idx  = blockIdx.x * 256 + threadIdx.x;  // 524288 total
    int s8   = idx & 255;                        // T/8
    int rest = idx >> 8;                         // (b*8+g)*128 + d
    int d    = rest & (HD-1);
    int bg   = rest >> 7;
    int b    = bg >> 3;
    int g    = bg & 7;
    int s0   = s8 * 8;
    const __bf16* src = qkv + (size_t)(b*SEQ + s0)*NQKV + VOFF + g*HD + d;
    bf16x8 v;
    #pragma unroll
    for (int u = 0; u < 8; ++u) v[u] = src[(size_t)u*NQKV];
    *(bf16x8*)(vt + (size_t)rest*SEQ + s0) = v;
}

// ---------------- flash attention: Q-tile 64, K-tile 64, 4 waves (16 q-rows each) ----
__global__ __launch_bounds__(256)
void flash_attn(const __bf16* __restrict__ qkv, const __bf16* __restrict__ vt,
                __bf16* __restrict__ O)
{
    __shared__ __bf16 Qs[64*128];   // [qrow][d]
    __shared__ __bf16 Ks[64*128];   // [srow][d]
    __shared__ __bf16 Vts[128*64];  // [d][s]
    __shared__ __bf16 Ps[64*64];    // [qrow][s]

    const int qt = blockIdx.x;      // 0..31
    const int bh = blockIdx.y;      // 0..63
    const int b  = bh >> 5;
    const int h  = bh & 31;
    const int g  = h >> 2;          // kv head (repeat_interleave: g = h / R)
    const int q0 = qt * 64;

    const int tid  = threadIdx.x;
    const int lane = tid & 63;
    const int w    = tid >> 6;
    const int quad = lane >> 4;
    const int l16  = lane & 15;

    const __bf16* Qb  = qkv + (size_t)(b*SEQ + q0)*NQKV + h*HD;
    const __bf16* Kb  = qkv + (size_t)(b*SEQ)*NQKV + KOFF + g*HD;
    const __bf16* Vtb = vt  + (size_t)((b*NKVH + g)*HD)*SEQ;

    #pragma unroll
    for (int r = 0; r < 4; ++r) {          // stage Q: 1024 x 16B
        int c = r*256 + tid;
        int row = c >> 4, c16 = c & 15;
        gl_lds16(Qb + (size_t)row*NQKV + c16*8, Qs + c*8);
    }

    f32x4 o_acc[8] = {};
    float m_i[4], l_i[4];
    #pragma unroll
    for (int r = 0; r < 4; ++r) { m_i[r] = -1e30f; l_i[r] = 0.f; }

    const int nkt = qt + 1;                // causal: skip fully-masked K-tiles
    for (int kt = 0; kt < nkt; ++kt) {
        const int s0 = kt * 64;
        __syncthreads();                   // prev iter LDS reads done (also drains Q loads at kt=0)
        #pragma unroll
        for (int r = 0; r < 4; ++r) {
            int c = r*256 + tid;
            { int row = c >> 4, c16 = c & 15;
              gl_lds16(Kb + (size_t)(s0 + row)*NQKV + c16*8, Ks + c*8); }
            { int dd = c >> 3, c8 = c & 7;
              gl_lds16(Vtb + (size_t)dd*SEQ + s0 + c8*8, Vts + c*8); }
        }
        __syncthreads();

        // S = Q K^T  (wave w owns q-rows w*16..w*16+15)
        f32x4 s_acc[4] = {};
        #pragma unroll
        for (int kk = 0; kk < 128; kk += 32) {
            bf16x8 aq = *(const bf16x8*)(Qs + (w*16 + l16)*128 + kk + quad*8);
            #pragma unroll
            for (int j = 0; j < 4; ++j) {
                bf16x8 bk = *(const bf16x8*)(Ks + (j*16 + l16)*128 + kk + quad*8);
                s_acc[j] = __builtin_amdgcn_mfma_f32_16x16x32_bf16(aq, bk, s_acc[j], 0,0,0);
            }
        }

        // causal mask (finite large-neg to avoid inf-inf NaN)
        #pragma unroll
        for (int j = 0; j < 4; ++j) {
            int col = s0 + j*16 + l16;
            #pragma unroll
            for (int r = 0; r < 4; ++r) {
                int qrow = q0 + w*16 + quad*4 + r;
                if (col > qrow) s_acc[j][r] = -1e30f;
            }
        }

        // online softmax (rows live across 16 lanes of a quad)
        float mnew[4], alpha[4], psum[4];
        #pragma unroll
        for (int r = 0; r < 4; ++r) {
            float pm = fmaxf(fmaxf(s_acc[0][r], s_acc[1][r]), fmaxf(s_acc[2][r], s_acc[3][r]));
            pm = fmaxf(pm, __shfl_xor(pm, 1));
            pm = fmaxf(pm, __shfl_xor(pm, 2));
            pm = fmaxf(pm, __shfl_xor(pm, 4));
            pm = fmaxf(pm, __shfl_xor(pm, 8));
            mnew[r]  = fmaxf(m_i[r], pm);
            alpha[r] = exp2f(m_i[r] - mnew[r]);
            m_i[r]   = mnew[r];
            psum[r]  = 0.f;
        }
        #pragma unroll
        for (int j = 0; j < 4; ++j) {
            #pragma unroll
            for (int r = 0; r < 4; ++r) {
                float p = exp2f(s_acc[j][r] - mnew[r]);
                psum[r] += p;
                Ps[(w*16 + quad*4 + r)*64 + j*16 + l16] = (__bf16)p;  // C-layout -> LDS
            }
        }
        #pragma unroll
        for (int r = 0; r < 4; ++r) {
            float ps = psum[r];
            ps += __shfl_xor(ps, 1);
            ps += __shfl_xor(ps, 2);
            ps += __shfl_xor(ps, 4);
            ps += __shfl_xor(ps, 8);
            l_i[r] = l_i[r]*alpha[r] + ps;
        }
        #pragma unroll
        for (int jt = 0; jt < 8; ++jt)
            #pragma unroll
            for (int r = 0; r < 4; ++r)
                o_acc[jt][r] *= alpha[r];

        // O += P V   (A from Ps in A-layout, B from Vts: contiguous-k reads)
        #pragma unroll
        for (int kk = 0; kk < 64; kk += 32) {
            bf16x8 ap = *(const bf16x8*)(Ps + (w*16 + l16)*64 + kk + quad*8);
            #pragma unroll
            for (int jt = 0; jt < 8; ++jt) {
                bf16x8 bv = *(const bf16x8*)(Vts + (jt*16 + l16)*64 + kk + quad*8);
                o_acc[jt] = __builtin_amdgcn_mfma_f32_16x16x32_bf16(ap, bv, o_acc[jt], 0,0,0);
            }
        }
    }

    float invl[4];
    #pragma unroll
    for (int r = 0; r < 4; ++r) invl[r] = 1.0f / l_i[r];
    #pragma unroll
    for (int jt = 0; jt < 8; ++jt) {
        #pragma unroll
        for (int r = 0; r < 4; ++r) {
            int row = q0 + w*16 + quad*4 + r;
            int col = h*HD + jt*16 + l16;
            O[(size_t)(b*SEQ + row)*DIM + col] = (__bf16)(o_acc[jt][r] * invl[r]);
        }
    }
}

extern "C" void kernel_launch(void* const* d_in, const int* in_sizes, int n_in,
                              void* d_out, int out_size, void* d_ws, size_t ws_size,
                              hipStream_t stream) {
    const float* x   = (const float*)d_in[0];
    const float* Wq  = (const float*)d_in[1];
    const float* Wkv = (const float*)d_in[2];
    const float* Wo  = (const float*)d_in[3];

    // workspace layout (bytes)
    const size_t OFF_XB   = 0;                       // 4096*4096 bf16 = 32 MB
    const size_t OFF_WQKV = 33554432;                // 6144*4096 bf16 = 48 MB
    const size_t OFF_WO   = 83886080;                // 4096*4096 bf16 = 32 MB
    const size_t OFF_QKV  = 117440512;               // 4096*6144 bf16 = 48 MB
    const size_t OFF_VT   = 167772160;               // 2*8*128*2048 bf16 = 8 MB
    const size_t OFF_OB   = 176160768;               // 4096*4096 bf16 = 32 MB
    const size_t NEEDED   = 209715200;               // 200 MB
    if (ws_size < NEEDED) return;                    // refuse OOB rather than corrupt

    char* ws = (char*)d_ws;
    __bf16* xb   = (__bf16*)(ws + OFF_XB);
    __bf16* wqkv = (__bf16*)(ws + OFF_WQKV);
    __bf16* wo   = (__bf16*)(ws + OFF_WO);
    __bf16* qkv  = (__bf16*)(ws + OFF_QKV);
    __bf16* vt   = (__bf16*)(ws + OFF_VT);
    __bf16* ob   = (__bf16*)(ws + OFF_OB);

    // casts (Wq and Wkv concatenated row-wise into wqkv)
    cast_f32_bf16<<<16777216/8/256, 256, 0, stream>>>(x,   xb,              16777216/8);
    cast_f32_bf16<<<16777216/8/256, 256, 0, stream>>>(Wq,  wqkv,            16777216/8);
    cast_f32_bf16<<< 8388608/8/256, 256, 0, stream>>>(Wkv, wqkv + 16777216,  8388608/8);
    cast_f32_bf16<<<16777216/8/256, 256, 0, stream>>>(Wo,  wo,              16777216/8);

    // fused QKV projection; Q cols scaled by log2(e)/sqrt(hd)
    gemm_bt<__bf16><<<dim3(NQKV/128, MROWS/128), 256, 0, stream>>>(
        xb, wqkv, qkv, MROWS, NQKV, DIM, QSCALE, DIM);

    transpose_v<<<524288/256, 256, 0, stream>>>(qkv, vt);

    flash_attn<<<dim3(SEQ/64, BATCH*NHEADS), 256, 0, stream>>>(qkv, vt, ob);

    // output projection -> fp32 d_out
    gemm_bt<float><<<dim3(DIM/128, MROWS/128), 256, 0, stream>>>(
        ob, wo, (float*)d_out, MROWS, DIM, DIM, 1.0f, 0);
}

// Round 2
// 967.259 us; speedup vs baseline: 1.4221x; 1.4221x over previous
//
#include <hip/hip_runtime.h>
#include <hip/hip_bf16.h>
#include <cstdint>
#include <type_traits>

#define DIM    4096
#define NHEADS 32
#define NKVH   8
#define HD     128
#define BATCH  2
#define SEQ    2048
#define MROWS  (BATCH*SEQ)      // 4096
#define NQKV   6144             // DIM + 2*NKVH*HD
#define KOFF   4096
#define VOFF   5120

typedef __attribute__((ext_vector_type(8))) __bf16 bf16x8;
typedef __attribute__((ext_vector_type(4))) float  f32x4;

// scale folded into Q: log2(e)/sqrt(HD) so softmax uses exp2 (native v_exp_f32)
#define QSCALE 0.1275174338f

__device__ __forceinline__ void gl_lds16(const __bf16* g, __bf16* l) {
    __builtin_amdgcn_global_load_lds(
        (const __attribute__((address_space(1))) void*)g,
        (__attribute__((address_space(3))) void*)l, 16, 0, 0);
}

// ---------------- fp32 -> bf16 cast (8 elem/thread) ----------------
__global__ void cast_f32_bf16(const float* __restrict__ s, __bf16* __restrict__ d, int n8) {
    int i = blockIdx.x * 256 + threadIdx.x;
    if (i >= n8) return;
    float4 a = ((const float4*)s)[2*i];
    float4 b = ((const float4*)s)[2*i+1];
    bf16x8 v;
    v[0]=(__bf16)a.x; v[1]=(__bf16)a.y; v[2]=(__bf16)a.z; v[3]=(__bf16)a.w;
    v[4]=(__bf16)b.x; v[5]=(__bf16)b.y; v[6]=(__bf16)b.z; v[7]=(__bf16)b.w;
    ((bf16x8*)d)[i] = v;
}

// ---------------- GEMM: C[m,n] = sum_k A[m,k]*B[n,k]  (both row-major, K contig) ----
// m97 structure + XOR-swizzled LDS (chunk ^= row&7) to kill 16-way read conflicts.
template<typename OutT>
__global__ __launch_bounds__(256)
void gemm_bt(const __bf16* __restrict__ A, const __bf16* __restrict__ Bm,
             OutT* __restrict__ C, int M, int N, int K,
             float scale, int scale_cols)
{
    __shared__ __bf16 As[128*64];
    __shared__ __bf16 Bs[128*64];
    const int tid  = threadIdx.x;
    const int lane = tid & 63;
    const int w    = tid >> 6;
    const int quad = lane >> 4;
    const int l16  = lane & 15;
    const int m0   = blockIdx.y * 128;
    const int n0   = blockIdx.x * 128;
    const int wm   = (w & 1) * 64;
    const int wn   = (w >> 1) * 64;

    const __bf16* Ab = A  + (size_t)m0 * K;
    const __bf16* Bb = Bm + (size_t)n0 * K;

    f32x4 acc[4][4] = {};

    for (int k0 = 0; k0 < K; k0 += 64) {
        __syncthreads();
        #pragma unroll
        for (int r = 0; r < 4; ++r) {
            int chunk = r*256 + tid;
            int row = chunk >> 3, c8 = chunk & 7;
            int c8s = c8 ^ (row & 7);                 // source-side swizzle
            gl_lds16(Ab + (size_t)row*K + k0 + c8s*8, As + chunk*8);
            gl_lds16(Bb + (size_t)row*K + k0 + c8s*8, Bs + chunk*8);
        }
        __syncthreads();
        #pragma unroll
        for (int t = 0; t < 2; ++t) {                 // kk = t*32
            bf16x8 af[4], bfr[4];
            #pragma unroll
            for (int i = 0; i < 4; ++i) {
                int row = wm + i*16 + l16;
                int cc  = (t*4 + quad) ^ (row & 7);
                af[i] = *(const bf16x8*)(As + row*64 + cc*8);
            }
            #pragma unroll
            for (int j = 0; j < 4; ++j) {
                int row = wn + j*16 + l16;
                int cc  = (t*4 + quad) ^ (row & 7);
                bfr[j] = *(const bf16x8*)(Bs + row*64 + cc*8);
            }
            #pragma unroll
            for (int i = 0; i < 4; ++i)
                #pragma unroll
                for (int j = 0; j < 4; ++j)
                    acc[i][j] = __builtin_amdgcn_mfma_f32_16x16x32_bf16(af[i], bfr[j], acc[i][j], 0,0,0);
        }
    }

    // C/D layout: col = lane&15, row = quad*4 + reg  [verified m89/m91]
    #pragma unroll
    for (int i = 0; i < 4; ++i) {
        #pragma unroll
        for (int j = 0; j < 4; ++j) {
            int col = n0 + wn + j*16 + l16;
            float sc = (col < scale_cols) ? scale : 1.0f;
            #pragma unroll
            for (int r = 0; r < 4; ++r) {
                int row = m0 + wm + i*16 + quad*4 + r;
                float v = acc[i][j][r] * sc;
                if constexpr (std::is_same<OutT, float>::value)
                    C[(size_t)row * N + col] = v;
                else
                    C[(size_t)row * N + col] = (__bf16)v;
            }
        }
    }
}

// ---------------- V transpose: vt[(b*8+g)*128 + d][s] = qkv[b*T+s][VOFF + g*128 + d] ----
__global__ void transpose_v(const __bf16* __restrict__ qkv, __bf16* __restrict__ vt) {
    int idx  = blockIdx.x * 256 + threadIdx.x;  // 524288 total
    int s8   = idx & 255;                        // T/8
    int rest = idx >> 8;                         // (b*8+g)*128 + d
    int d    = rest & (HD-1);
    int bg   = rest >> 7;
    int b    = bg >> 3;
    int g    = bg & 7;
    int s0   = s8 * 8;
    const __bf16* src = qkv + (size_t)(b*SEQ + s0)*NQKV + VOFF + g*HD + d;
    bf16x8 v;
    #pragma unroll
    for (int u = 0; u < 8; ++u) v[u] = src[(size_t)u*NQKV];
    *(bf16x8*)(vt + (size_t)rest*SEQ + s0) = v;
}

// ---------------- flash attention: Q-tile 64 (regs), K-tile 64, swizzled LDS ----
#define PSTR 72   // Ps row stride (pad 64 -> 72: +4 banks/row, 2-way max)

__global__ __launch_bounds__(256)
void flash_attn(const __bf16* __restrict__ qkv, const __bf16* __restrict__ vt,
                __bf16* __restrict__ O)
{
    __shared__ __bf16 Ks[64*128];   // [srow][d]   swizzled chunks
    __shared__ __bf16 Vts[128*64];  // [d][s]      swizzled chunks
    __shared__ __bf16 Ps[64*PSTR];  // [qrow][s]   padded

    const int qt = (gridDim.x - 1) - blockIdx.x;   // long blocks dispatch first
    const int bh = blockIdx.y;      // 0..63
    const int b  = bh >> 5;
    const int h  = bh & 31;
    const int g  = h >> 2;          // kv head (repeat_interleave)
    const int q0 = qt * 64;

    const int tid  = threadIdx.x;
    const int lane = tid & 63;
    const int w    = tid >> 6;
    const int quad = lane >> 4;
    const int l16  = lane & 15;

    const __bf16* Qb  = qkv + (size_t)(b*SEQ + q0)*NQKV + h*HD;
    const __bf16* Kb  = qkv + (size_t)(b*SEQ)*NQKV + KOFF + g*HD;
    const __bf16* Vtb = vt  + (size_t)((b*NKVH + g)*HD)*SEQ;

    // Q fragments in registers (A-layout): wave w owns q-rows w*16..w*16+15
    bf16x8 qf[4];
    #pragma unroll
    for (int t = 0; t < 4; ++t)
        qf[t] = *(const bf16x8*)(Qb + (size_t)(w*16 + l16)*NQKV + t*32 + quad*8);

    f32x4 o_acc[8] = {};
    float m_i[4], l_i[4];
    #pragma unroll
    for (int r = 0; r < 4; ++r) { m_i[r] = -1e30f; l_i[r] = 0.f; }

    const int nkt = qt + 1;                // causal: skip fully-masked K-tiles
    for (int kt = 0; kt < nkt; ++kt) {
        const int s0 = kt * 64;
        __syncthreads();                   // prev-iter LDS reads done
        #pragma unroll
        for (int r = 0; r < 4; ++r) {
            int c = r*256 + tid;
            { int row = c >> 4, c16 = c & 15;
              int c16s = c16 ^ (row & 7);
              gl_lds16(Kb + (size_t)(s0 + row)*NQKV + c16s*8, Ks + c*8); }
            { int dd = c >> 3, c8 = c & 7;
              int c8s = c8 ^ (dd & 7);
              gl_lds16(Vtb + (size_t)dd*SEQ + s0 + c8s*8, Vts + c*8); }
        }
        __syncthreads();

        // S = Q K^T
        f32x4 s_acc[4] = {};
        #pragma unroll
        for (int t = 0; t < 4; ++t) {
            #pragma unroll
            for (int j = 0; j < 4; ++j) {
                int row = j*16 + l16;
                int cc  = (t*4 + quad) ^ (row & 7);
                bf16x8 bk = *(const bf16x8*)(Ks + row*128 + cc*8);
                s_acc[j] = __builtin_amdgcn_mfma_f32_16x16x32_bf16(qf[t], bk, s_acc[j], 0,0,0);
            }
        }

        // causal mask only on the diagonal tile
        if (kt == nkt - 1) {
            #pragma unroll
            for (int j = 0; j < 4; ++j) {
                int col = s0 + j*16 + l16;
                #pragma unroll
                for (int r = 0; r < 4; ++r) {
                    int qrow = q0 + w*16 + quad*4 + r;
                    if (col > qrow) s_acc[j][r] = -1e30f;
                }
            }
        }

        // online softmax (rows live across 16 lanes of a quad)
        float mnew[4], alpha[4], psum[4];
        #pragma unroll
        for (int r = 0; r < 4; ++r) {
            float pm = fmaxf(fmaxf(s_acc[0][r], s_acc[1][r]), fmaxf(s_acc[2][r], s_acc[3][r]));
            pm = fmaxf(pm, __shfl_xor(pm, 1));
            pm = fmaxf(pm, __shfl_xor(pm, 2));
            pm = fmaxf(pm, __shfl_xor(pm, 4));
            pm = fmaxf(pm, __shfl_xor(pm, 8));
            mnew[r]  = fmaxf(m_i[r], pm);
            alpha[r] = exp2f(m_i[r] - mnew[r]);
            m_i[r]   = mnew[r];
            psum[r]  = 0.f;
        }
        #pragma unroll
        for (int j = 0; j < 4; ++j) {
            #pragma unroll
            for (int r = 0; r < 4; ++r) {
                float p = exp2f(s_acc[j][r] - mnew[r]);
                psum[r] += p;
                Ps[(w*16 + quad*4 + r)*PSTR + j*16 + l16] = (__bf16)p;
            }
        }
        #pragma unroll
        for (int r = 0; r < 4; ++r) {
            float ps = psum[r];
            ps += __shfl_xor(ps, 1);
            ps += __shfl_xor(ps, 2);
            ps += __shfl_xor(ps, 4);
            ps += __shfl_xor(ps, 8);
            l_i[r] = l_i[r]*alpha[r] + ps;
        }
        #pragma unroll
        for (int jt = 0; jt < 8; ++jt)
            #pragma unroll
            for (int r = 0; r < 4; ++r)
                o_acc[jt][r] *= alpha[r];

        // O += P V
        #pragma unroll
        for (int t = 0; t < 2; ++t) {
            bf16x8 ap = *(const bf16x8*)(Ps + (w*16 + l16)*PSTR + t*32 + quad*8);
            #pragma unroll
            for (int jt = 0; jt < 8; ++jt) {
                int row = jt*16 + l16;
                int cc  = (t*4 + quad) ^ (row & 7);
                bf16x8 bv = *(const bf16x8*)(Vts + row*64 + cc*8);
                o_acc[jt] = __builtin_amdgcn_mfma_f32_16x16x32_bf16(ap, bv, o_acc[jt], 0,0,0);
            }
        }
    }

    float invl[4];
    #pragma unroll
    for (int r = 0; r < 4; ++r) invl[r] = 1.0f / l_i[r];
    #pragma unroll
    for (int jt = 0; jt < 8; ++jt) {
        #pragma unroll
        for (int r = 0; r < 4; ++r) {
            int row = q0 + w*16 + quad*4 + r;
            int col = h*HD + jt*16 + l16;
            O[(size_t)(b*SEQ + row)*DIM + col] = (__bf16)(o_acc[jt][r] * invl[r]);
        }
    }
}

extern "C" void kernel_launch(void* const* d_in, const int* in_sizes, int n_in,
                              void* d_out, int out_size, void* d_ws, size_t ws_size,
                              hipStream_t stream) {
    const float* x   = (const float*)d_in[0];
    const float* Wq  = (const float*)d_in[1];
    const float* Wkv = (const float*)d_in[2];
    const float* Wo  = (const float*)d_in[3];

    // workspace layout (bytes)
    const size_t OFF_XB   = 0;                       // 4096*4096 bf16 = 32 MB
    const size_t OFF_WQKV = 33554432;                // 6144*4096 bf16 = 48 MB
    const size_t OFF_WO   = 83886080;                // 4096*4096 bf16 = 32 MB
    const size_t OFF_QKV  = 117440512;               // 4096*6144 bf16 = 48 MB
    const size_t OFF_VT   = 167772160;               // 2*8*128*2048 bf16 = 8 MB
    const size_t OFF_OB   = 176160768;               // 4096*4096 bf16 = 32 MB
    const size_t NEEDED   = 209715200;               // 200 MB
    if (ws_size < NEEDED) return;

    char* ws = (char*)d_ws;
    __bf16* xb   = (__bf16*)(ws + OFF_XB);
    __bf16* wqkv = (__bf16*)(ws + OFF_WQKV);
    __bf16* wo   = (__bf16*)(ws + OFF_WO);
    __bf16* qkv  = (__bf16*)(ws + OFF_QKV);
    __bf16* vt   = (__bf16*)(ws + OFF_VT);
    __bf16* ob   = (__bf16*)(ws + OFF_OB);

    cast_f32_bf16<<<16777216/8/256, 256, 0, stream>>>(x,   xb,              16777216/8);
    cast_f32_bf16<<<16777216/8/256, 256, 0, stream>>>(Wq,  wqkv,            16777216/8);
    cast_f32_bf16<<< 8388608/8/256, 256, 0, stream>>>(Wkv, wqkv + 16777216,  8388608/8);
    cast_f32_bf16<<<16777216/8/256, 256, 0, stream>>>(Wo,  wo,              16777216/8);

    gemm_bt<__bf16><<<dim3(NQKV/128, MROWS/128), 256, 0, stream>>>(
        xb, wqkv, qkv, MROWS, NQKV, DIM, QSCALE, DIM);

    transpose_v<<<524288/256, 256, 0, stream>>>(qkv, vt);

    flash_attn<<<dim3(SEQ/64, BATCH*NHEADS), 256, 0, stream>>>(qkv, vt, ob);

    gemm_bt<float><<<dim3(DIM/128, MROWS/128), 256, 0, stream>>>(
        ob, wo, (float*)d_out, MROWS, DIM, DIM, 1.0f, 0);
}

// Round 3
// 850.643 us; speedup vs baseline: 1.6170x; 1.1371x over previous
//
#include <hip/hip_runtime.h>
#include <hip/hip_bf16.h>
#include <cstdint>
#include <type_traits>

#define DIM    4096
#define NHEADS 32
#define NKVH   8
#define HD     128
#define BATCH  2
#define SEQ    2048
#define MROWS  (BATCH*SEQ)      // 4096
#define NQKV   6144             // DIM + 2*NKVH*HD
#define KOFF   4096
#define VOFF   5120

typedef __attribute__((ext_vector_type(8))) __bf16 bf16x8;
typedef __attribute__((ext_vector_type(4))) __bf16 bf16x4;
typedef __attribute__((ext_vector_type(4))) float  f32x4;

// scale folded into Q: log2(e)/sqrt(HD) so softmax uses exp2 (native v_exp_f32)
#define QSCALE 0.1275174338f

__device__ __forceinline__ void gl_lds16(const __bf16* g, __bf16* l) {
    __builtin_amdgcn_global_load_lds(
        (const __attribute__((address_space(1))) void*)g,
        (__attribute__((address_space(3))) void*)l, 16, 0, 0);
}

// ---------------- fp32 -> bf16 cast (8 elem/thread) ----------------
__global__ void cast_f32_bf16(const float* __restrict__ s, __bf16* __restrict__ d, int n8) {
    int i = blockIdx.x * 256 + threadIdx.x;
    if (i >= n8) return;
    float4 a = ((const float4*)s)[2*i];
    float4 b = ((const float4*)s)[2*i+1];
    bf16x8 v;
    v[0]=(__bf16)a.x; v[1]=(__bf16)a.y; v[2]=(__bf16)a.z; v[3]=(__bf16)a.w;
    v[4]=(__bf16)b.x; v[5]=(__bf16)b.y; v[6]=(__bf16)b.z; v[7]=(__bf16)b.w;
    ((bf16x8*)d)[i] = v;
}

// ---------------- GEMM: C[m,n] = sum_k A[m,k]*B[n,k]  (both row-major, K contig) ----
// m97 structure + XOR-swizzled LDS (chunk ^= row&7) to kill 16-way read conflicts.
template<typename OutT>
__global__ __launch_bounds__(256)
void gemm_bt(const __bf16* __restrict__ A, const __bf16* __restrict__ Bm,
             OutT* __restrict__ C, int M, int N, int K,
             float scale, int scale_cols)
{
    __shared__ __bf16 As[128*64];
    __shared__ __bf16 Bs[128*64];
    const int tid  = threadIdx.x;
    const int lane = tid & 63;
    const int w    = tid >> 6;
    const int quad = lane >> 4;
    const int l16  = lane & 15;
    const int m0   = blockIdx.y * 128;
    const int n0   = blockIdx.x * 128;
    const int wm   = (w & 1) * 64;
    const int wn   = (w >> 1) * 64;

    const __bf16* Ab = A  + (size_t)m0 * K;
    const __bf16* Bb = Bm + (size_t)n0 * K;

    f32x4 acc[4][4] = {};

    for (int k0 = 0; k0 < K; k0 += 64) {
        __syncthreads();
        #pragma unroll
        for (int r = 0; r < 4; ++r) {
            int chunk = r*256 + tid;
            int row = chunk >> 3, c8 = chunk & 7;
            int c8s = c8 ^ (row & 7);                 // source-side swizzle
            gl_lds16(Ab + (size_t)row*K + k0 + c8s*8, As + chunk*8);
            gl_lds16(Bb + (size_t)row*K + k0 + c8s*8, Bs + chunk*8);
        }
        __syncthreads();
        #pragma unroll
        for (int t = 0; t < 2; ++t) {                 // kk = t*32
            bf16x8 af[4], bfr[4];
            #pragma unroll
            for (int i = 0; i < 4; ++i) {
                int row = wm + i*16 + l16;
                int cc  = (t*4 + quad) ^ (row & 7);
                af[i] = *(const bf16x8*)(As + row*64 + cc*8);
            }
            #pragma unroll
            for (int j = 0; j < 4; ++j) {
                int row = wn + j*16 + l16;
                int cc  = (t*4 + quad) ^ (row & 7);
                bfr[j] = *(const bf16x8*)(Bs + row*64 + cc*8);
            }
            #pragma unroll
            for (int i = 0; i < 4; ++i)
                #pragma unroll
                for (int j = 0; j < 4; ++j)
                    acc[i][j] = __builtin_amdgcn_mfma_f32_16x16x32_bf16(af[i], bfr[j], acc[i][j], 0,0,0);
        }
    }

    // C/D layout: col = lane&15, row = quad*4 + reg  [verified m89/m91]
    #pragma unroll
    for (int i = 0; i < 4; ++i) {
        #pragma unroll
        for (int j = 0; j < 4; ++j) {
            int col = n0 + wn + j*16 + l16;
            float sc = (col < scale_cols) ? scale : 1.0f;
            #pragma unroll
            for (int r = 0; r < 4; ++r) {
                int row = m0 + wm + i*16 + quad*4 + r;
                float v = acc[i][j][r] * sc;
                if constexpr (std::is_same<OutT, float>::value)
                    C[(size_t)row * N + col] = v;
                else
                    C[(size_t)row * N + col] = (__bf16)v;
            }
        }
    }
}

// ---------------- V transpose: vt[(b*8+g)*128 + d][s] = qkv[b*T+s][VOFF + g*128 + d] ----
__global__ void transpose_v(const __bf16* __restrict__ qkv, __bf16* __restrict__ vt) {
    int idx  = blockIdx.x * 256 + threadIdx.x;  // 524288 total
    int s8   = idx & 255;                        // T/8
    int rest = idx >> 8;                         // (b*8+g)*128 + d
    int d    = rest & (HD-1);
    int bg   = rest >> 7;
    int b    = bg >> 3;
    int g    = bg & 7;
    int s0   = s8 * 8;
    const __bf16* src = qkv + (size_t)(b*SEQ + s0)*NQKV + VOFF + g*HD + d;
    bf16x8 v;
    #pragma unroll
    for (int u = 0; u < 8; ++u) v[u] = src[(size_t)u*NQKV];
    *(bf16x8*)(vt + (size_t)rest*SEQ + s0) = v;
}

// ---------------- flash attention: S^T formulation ----
// S^T = K·Q^T puts a whole q-row's scores in ONE lane (col=l16=q-row):
// row max/sum = in-lane reg tree + 2 shfls (vs 4-row x 4-step butterflies).
// Ps: XOR-swizzled stride-64 (no pad) -> LDS = 40960 B = exactly 4 blocks/CU.
__global__ __launch_bounds__(256, 4)
void flash_attn(const __bf16* __restrict__ qkv, const __bf16* __restrict__ vt,
                __bf16* __restrict__ O)
{
    __shared__ __bf16 Ks[64*128];   // [srow][d]   swizzled chunks
    __shared__ __bf16 Vts[128*64];  // [d][s]      swizzled chunks
    __shared__ __bf16 Ps[64*64];    // [qrow][s]   chunk-swizzled, per-wave rows

    const int qt = (gridDim.x - 1) - blockIdx.x;   // long blocks dispatch first
    const int bh = blockIdx.y;      // 0..63
    const int b  = bh >> 5;
    const int h  = bh & 31;
    const int g  = h >> 2;          // kv head (repeat_interleave)
    const int q0 = qt * 64;

    const int tid  = threadIdx.x;
    const int lane = tid & 63;
    const int w    = tid >> 6;
    const int quad = lane >> 4;
    const int l16  = lane & 15;
    const int psw  = (l16 & 7) << 1;   // Ps chunk swizzle (even -> keeps 16B pairs)

    const __bf16* Qb  = qkv + (size_t)(b*SEQ + q0)*NQKV + h*HD;
    const __bf16* Kb  = qkv + (size_t)(b*SEQ)*NQKV + KOFF + g*HD;
    const __bf16* Vtb = vt  + (size_t)((b*NKVH + g)*HD)*SEQ;

    // Q fragments in registers: wave w owns q-rows w*16..w*16+15 (lane's row = l16)
    bf16x8 qf[4];
    #pragma unroll
    for (int t = 0; t < 4; ++t)
        qf[t] = *(const bf16x8*)(Qb + (size_t)(w*16 + l16)*NQKV + t*32 + quad*8);

    f32x4 o_acc[8] = {};
    float m_i = -1e30f, l_i = 0.f;     // per-lane scalars: q-row = w*16 + l16
    const int myrow = q0 + w*16 + l16;

    const int nkt = qt + 1;                // causal: skip fully-masked K-tiles
    for (int kt = 0; kt < nkt; ++kt) {
        const int s0 = kt * 64;
        __syncthreads();                   // prev-iter Ks/Vts reads done
        #pragma unroll
        for (int r = 0; r < 4; ++r) {
            int c = r*256 + tid;
            { int row = c >> 4, c16 = c & 15;
              int c16s = c16 ^ (row & 7);
              gl_lds16(Kb + (size_t)(s0 + row)*NQKV + c16s*8, Ks + c*8); }
            { int dd = c >> 3, c8 = c & 7;
              int c8s = c8 ^ (dd & 7);
              gl_lds16(Vtb + (size_t)dd*SEQ + s0 + c8s*8, Vts + c*8); }
        }
        __syncthreads();

        // S^T = K Q^T : C col = l16 = q-row, row = quad*4+r = s (within tile j)
        f32x4 s_acc[4] = {};
        #pragma unroll
        for (int t = 0; t < 4; ++t) {
            #pragma unroll
            for (int j = 0; j < 4; ++j) {
                int row = j*16 + l16;
                int cc  = (t*4 + quad) ^ (row & 7);
                bf16x8 bk = *(const bf16x8*)(Ks + row*128 + cc*8);
                s_acc[j] = __builtin_amdgcn_mfma_f32_16x16x32_bf16(bk, qf[t], s_acc[j], 0,0,0);
            }
        }

        // causal mask on the diagonal tile (s = s0 + j*16 + quad*4 + r)
        if (kt == nkt - 1) {
            #pragma unroll
            for (int j = 0; j < 4; ++j)
                #pragma unroll
                for (int r = 0; r < 4; ++r)
                    if (s0 + j*16 + quad*4 + r > myrow) s_acc[j][r] = -1e30f;
        }

        // online softmax — in-lane over 16 regs, then 2 shfls across quads
        float pm = s_acc[0][0];
        #pragma unroll
        for (int j = 0; j < 4; ++j)
            #pragma unroll
            for (int r = 0; r < 4; ++r)
                pm = fmaxf(pm, s_acc[j][r]);
        pm = fmaxf(pm, __shfl_xor(pm, 16));
        pm = fmaxf(pm, __shfl_xor(pm, 32));
        float mnew  = fmaxf(m_i, pm);
        float alpha = exp2f(m_i - mnew);
        m_i = mnew;

        float psum = 0.f;
        #pragma unroll
        for (int j = 0; j < 4; ++j) {
            bf16x4 pv;
            #pragma unroll
            for (int r = 0; r < 4; ++r) {
                float p = exp2f(s_acc[j][r] - mnew);
                psum += p;
                pv[r] = (__bf16)p;
            }
            int cs = (j*4 + quad) ^ psw;
            *(bf16x4*)(Ps + (w*16 + l16)*64 + cs*4) = pv;   // ds_write_b64
        }
        psum += __shfl_xor(psum, 16);
        psum += __shfl_xor(psum, 32);
        l_i = l_i*alpha + psum;

        // broadcast alpha to O-rows (o_acc row = quad*4+r, alpha lives at lane l16=row)
        float av[4];
        #pragma unroll
        for (int r = 0; r < 4; ++r) av[r] = __shfl(alpha, quad*4 + r);
        #pragma unroll
        for (int jt = 0; jt < 8; ++jt)
            #pragma unroll
            for (int r = 0; r < 4; ++r)
                o_acc[jt][r] *= av[r];

        // O += P V  (Ps rows are per-wave: no barrier needed, lgkmcnt suffices)
        #pragma unroll
        for (int t = 0; t < 2; ++t) {
            int cs = (t*8 + quad*2) ^ psw;
            bf16x8 ap = *(const bf16x8*)(Ps + (w*16 + l16)*64 + cs*4);
            #pragma unroll
            for (int jt = 0; jt < 8; ++jt) {
                int row = jt*16 + l16;
                int cc  = (t*4 + quad) ^ (row & 7);
                bf16x8 bv = *(const bf16x8*)(Vts + row*64 + cc*8);
                o_acc[jt] = __builtin_amdgcn_mfma_f32_16x16x32_bf16(ap, bv, o_acc[jt], 0,0,0);
            }
        }
    }

    float inv = 1.0f / l_i;
    float ivr[4];
    #pragma unroll
    for (int r = 0; r < 4; ++r) ivr[r] = __shfl(inv, quad*4 + r);
    #pragma unroll
    for (int jt = 0; jt < 8; ++jt) {
        #pragma unroll
        for (int r = 0; r < 4; ++r) {
            int row = q0 + w*16 + quad*4 + r;
            int col = h*HD + jt*16 + l16;
            O[(size_t)(b*SEQ + row)*DIM + col] = (__bf16)(o_acc[jt][r] * ivr[r]);
        }
    }
}

extern "C" void kernel_launch(void* const* d_in, const int* in_sizes, int n_in,
                              void* d_out, int out_size, void* d_ws, size_t ws_size,
                              hipStream_t stream) {
    const float* x   = (const float*)d_in[0];
    const float* Wq  = (const float*)d_in[1];
    const float* Wkv = (const float*)d_in[2];
    const float* Wo  = (const float*)d_in[3];

    // workspace layout (bytes)
    const size_t OFF_XB   = 0;                       // 4096*4096 bf16 = 32 MB
    const size_t OFF_WQKV = 33554432;                // 6144*4096 bf16 = 48 MB
    const size_t OFF_WO   = 83886080;                // 4096*4096 bf16 = 32 MB
    const size_t OFF_QKV  = 117440512;               // 4096*6144 bf16 = 48 MB
    const size_t OFF_VT   = 167772160;               // 2*8*128*2048 bf16 = 8 MB
    const size_t OFF_OB   = 176160768;               // 4096*4096 bf16 = 32 MB
    const size_t NEEDED   = 209715200;               // 200 MB
    if (ws_size < NEEDED) return;

    char* ws = (char*)d_ws;
    __bf16* xb   = (__bf16*)(ws + OFF_XB);
    __bf16* wqkv = (__bf16*)(ws + OFF_WQKV);
    __bf16* wo   = (__bf16*)(ws + OFF_WO);
    __bf16* qkv  = (__bf16*)(ws + OFF_QKV);
    __bf16* vt   = (__bf16*)(ws + OFF_VT);
    __bf16* ob   = (__bf16*)(ws + OFF_OB);

    cast_f32_bf16<<<16777216/8/256, 256, 0, stream>>>(x,   xb,              16777216/8);
    cast_f32_bf16<<<16777216/8/256, 256, 0, stream>>>(Wq,  wqkv,            16777216/8);
    cast_f32_bf16<<< 8388608/8/256, 256, 0, stream>>>(Wkv, wqkv + 16777216,  8388608/8);
    cast_f32_bf16<<<16777216/8/256, 256, 0, stream>>>(Wo,  wo,              16777216/8);

    gemm_bt<__bf16><<<dim3(NQKV/128, MROWS/128), 256, 0, stream>>>(
        xb, wqkv, qkv, MROWS, NQKV, DIM, QSCALE, DIM);

    transpose_v<<<524288/256, 256, 0, stream>>>(qkv, vt);

    flash_attn<<<dim3(SEQ/64, BATCH*NHEADS), 256, 0, stream>>>(qkv, vt, ob);

    gemm_bt<float><<<dim3(DIM/128, MROWS/128), 256, 0, stream>>>(
        ob, wo, (float*)d_out, MROWS, DIM, DIM, 1.0f, 0);
}